// Round 1
// baseline (109.581 us; speedup 1.0000x reference)
//
#include <hip/hip_runtime.h>

// ConcatCritic: scores[i,j] = W2 . relu(x_i@W1x + y_j@W1y + b1) + b2
// B=512, DIM_X=DIM_Y=128, HIDDEN=512. All fp32.

#define BATCH 512
#define DX    128
#define HID   512

// ---------------- Kernel A: projection ----------------
// hxy rows [0,512)    = x @ W1[:128]            (hx)
// hxy rows [512,1024) = y @ W1[128:256] + b1    (hy, bias folded here)
__global__ __launch_bounds__(256) void proj_kernel(
    const float* __restrict__ x, const float* __restrict__ y,
    const float* __restrict__ W1, const float* __restrict__ b1,
    float* __restrict__ hxy)
{
    const int part = blockIdx.y;               // 0 -> x block, 1 -> y block
    const float* __restrict__ src = part ? y : x;
    const float* __restrict__ W   = W1 + part * DX * HID;
    const int row0 = blockIdx.x * 8;

    __shared__ float s[8][DX];                 // 8 input rows, 4 KiB
    for (int t = threadIdx.x; t < 8 * DX; t += 256) {
        const int r = t >> 7, k = t & (DX - 1);
        s[r][k] = src[(row0 + r) * DX + k];
    }
    __syncthreads();

    #pragma unroll
    for (int half = 0; half < 2; ++half) {
        const int h = half * 256 + threadIdx.x;
        float acc[8] = {0.f, 0.f, 0.f, 0.f, 0.f, 0.f, 0.f, 0.f};
        for (int k = 0; k < DX; ++k) {
            const float w = W[k * HID + h];    // coalesced across threads
            #pragma unroll
            for (int r = 0; r < 8; ++r) acc[r] = fmaf(s[r][k], w, acc[r]);
        }
        const float bias = part ? b1[h] : 0.0f;
        #pragma unroll
        for (int r = 0; r < 8; ++r)
            hxy[(part * BATCH + row0 + r) * HID + h] = acc[r] + bias;
    }
}

// ---------------- Kernel B: broadcast + relu + weighted reduce ----------------
// 32x32 (i,j) tile per block, 256 threads, 2x2 outputs per thread.
// LDS stride 129 dwords: inner-loop scalar reads are bank-conflict-free
// (bank = (row*129 + h) % 32 = (row + h) % 32, rows distinct mod 32).
#define TB   32
#define HC   128
#define LSTR 129

__global__ __launch_bounds__(256) void score_kernel(
    const float* __restrict__ hxy, const float* __restrict__ W2,
    const float* __restrict__ b2, float* __restrict__ out)
{
    __shared__ float sA[TB * LSTR];            // hx tile rows (i)
    __shared__ float sB[TB * LSTR];            // hy tile rows (j)
    __shared__ float sW[HC];

    const int i0 = blockIdx.y * TB;
    const int j0 = blockIdx.x * TB;
    const int tid = threadIdx.x;
    const int tx = tid & 15;                   // j direction (16 groups of 2)
    const int ty = tid >> 4;                   // i direction (16 groups of 2)

    float acc00 = 0.f, acc01 = 0.f, acc10 = 0.f, acc11 = 0.f;

    for (int h0 = 0; h0 < HID; h0 += HC) {
        // ---- stage 32x128 of hx and hy (vector global loads, scalar LDS writes)
        for (int s = tid; s < TB * (HC / 4); s += 256) {   // 1024 float4 slots
            const int row = s >> 5;                        // 32 quads per row
            const int q4  = (s & 31) << 2;
            const float4 va = *(const float4*)&hxy[(i0 + row) * HID + h0 + q4];
            const float4 vb = *(const float4*)&hxy[(BATCH + j0 + row) * HID + h0 + q4];
            float* pa = &sA[row * LSTR + q4];
            float* pb = &sB[row * LSTR + q4];
            pa[0] = va.x; pa[1] = va.y; pa[2] = va.z; pa[3] = va.w;
            pb[0] = vb.x; pb[1] = vb.y; pb[2] = vb.z; pb[3] = vb.w;
        }
        if (tid < HC) sW[tid] = W2[h0 + tid];
        __syncthreads();

        // ---- inner reduce over this h chunk
        const float* pa0 = &sA[(2 * ty)     * LSTR];
        const float* pa1 = &sA[(2 * ty + 1) * LSTR];
        const float* pb0 = &sB[(2 * tx)     * LSTR];
        const float* pb1 = &sB[(2 * tx + 1) * LSTR];
        #pragma unroll 4
        for (int h = 0; h < HC; ++h) {
            const float w  = sW[h];
            const float a0 = pa0[h];
            const float a1 = pa1[h];
            const float b0v = pb0[h];
            const float b1v = pb1[h];
            acc00 = fmaf(fmaxf(a0 + b0v, 0.f), w, acc00);
            acc01 = fmaf(fmaxf(a0 + b1v, 0.f), w, acc01);
            acc10 = fmaf(fmaxf(a1 + b0v, 0.f), w, acc10);
            acc11 = fmaf(fmaxf(a1 + b1v, 0.f), w, acc11);
        }
        __syncthreads();
    }

    const float bs = b2[0];
    const int i = i0 + 2 * ty;
    const int j = j0 + 2 * tx;
    float2 r0 = make_float2(acc00 + bs, acc01 + bs);
    float2 r1 = make_float2(acc10 + bs, acc11 + bs);
    *(float2*)&out[i * BATCH + j]       = r0;
    *(float2*)&out[(i + 1) * BATCH + j] = r1;
}

extern "C" void kernel_launch(void* const* d_in, const int* in_sizes, int n_in,
                              void* d_out, int out_size, void* d_ws, size_t ws_size,
                              hipStream_t stream) {
    const float* x  = (const float*)d_in[0];
    const float* y  = (const float*)d_in[1];
    const float* W1 = (const float*)d_in[2];
    const float* b1 = (const float*)d_in[3];
    const float* W2 = (const float*)d_in[4];
    const float* b2 = (const float*)d_in[5];
    float* out = (float*)d_out;
    float* hxy = (float*)d_ws;   // 1024 * 512 floats = 2 MiB scratch

    proj_kernel<<<dim3(BATCH / 8, 2), 256, 0, stream>>>(x, y, W1, b1, hxy);
    score_kernel<<<dim3(BATCH / TB, BATCH / TB), 256, 0, stream>>>(hxy, W2, b2, out);
}

// Round 2
// 94.300 us; speedup vs baseline: 1.1620x; 1.1620x over previous
//
#include <hip/hip_runtime.h>

// ConcatCritic: scores[i,j] = W2 . relu(x_i@W1x + y_j@W1y + b1) + b2
// B=512, DIM_X=DIM_Y=128, HIDDEN=512. All fp32.
//
// R2: H split across blockIdx.z (4 chunks of 128) -> 1024 blocks = 4 blocks/CU
//     = 4 waves/SIMD (was 1). Single LDS stage per block, atomicAdd epilogue
//     into memset-zeroed out. proj widened to 256 blocks.

#define BATCH 512
#define DX    128
#define HID   512

// ---------------- Kernel A: projection ----------------
// hxy rows [0,512)    = x @ W1[:128]            (hx)
// hxy rows [512,1024) = y @ W1[128:256] + b1    (hy, bias folded)
__global__ __launch_bounds__(256) void proj_kernel(
    const float* __restrict__ x, const float* __restrict__ y,
    const float* __restrict__ W1, const float* __restrict__ b1,
    float* __restrict__ hxy)
{
    const int part = blockIdx.y;               // 0 -> x block, 1 -> y block
    const float* __restrict__ src = part ? y : x;
    const float* __restrict__ W   = W1 + part * DX * HID;
    const int row0 = blockIdx.x * 4;

    __shared__ float s[4][DX];                 // 4 input rows, 2 KiB
    for (int t = threadIdx.x; t < 4 * DX; t += 256) {
        const int r = t >> 7, k = t & (DX - 1);
        s[r][k] = src[(row0 + r) * DX + k];
    }
    __syncthreads();

    #pragma unroll
    for (int half = 0; half < 2; ++half) {
        const int h = half * 256 + threadIdx.x;
        float acc[4] = {0.f, 0.f, 0.f, 0.f};
        for (int k = 0; k < DX; ++k) {
            const float w = W[k * HID + h];    // coalesced across threads
            #pragma unroll
            for (int r = 0; r < 4; ++r) acc[r] = fmaf(s[r][k], w, acc[r]);
        }
        const float bias = part ? b1[h] : 0.0f;
        #pragma unroll
        for (int r = 0; r < 4; ++r)
            hxy[(part * BATCH + row0 + r) * HID + h] = acc[r] + bias;
    }
}

// ---------------- Kernel B: broadcast + relu + weighted reduce ----------------
// 32x32 (i,j) tile per block, 256 threads, 2x2 outputs/thread, one 128-h chunk
// per block (blockIdx.z selects chunk). LDS stride 129: scalar inner reads are
// bank-conflict-free (bank = (row + h) % 32, distinct rows -> distinct banks,
// same-row reads broadcast).
#define TB   32
#define HC   128
#define LSTR 129

__global__ __launch_bounds__(256, 4) void score_kernel(
    const float* __restrict__ hxy, const float* __restrict__ W2,
    const float* __restrict__ b2, float* __restrict__ out)
{
    __shared__ float sA[TB * LSTR];            // hx tile rows (i), 16.1 KiB
    __shared__ float sB[TB * LSTR];            // hy tile rows (j)
    __shared__ float sW[HC];

    const int i0 = blockIdx.y * TB;
    const int j0 = blockIdx.x * TB;
    const int h0 = blockIdx.z * HC;
    const int tid = threadIdx.x;
    const int tx = tid & 15;                   // j direction (16 groups of 2)
    const int ty = tid >> 4;                   // i direction (16 groups of 2)

    // ---- stage 32x128 of hx and hy (float4 global loads)
    for (int s = tid; s < TB * (HC / 4); s += 256) {   // 1024 float4 slots
        const int row = s >> 5;                        // 32 quads per row
        const int q4  = (s & 31) << 2;
        const float4 va = *(const float4*)&hxy[(i0 + row) * HID + h0 + q4];
        const float4 vb = *(const float4*)&hxy[(BATCH + j0 + row) * HID + h0 + q4];
        float* pa = &sA[row * LSTR + q4];
        float* pb = &sB[row * LSTR + q4];
        pa[0] = va.x; pa[1] = va.y; pa[2] = va.z; pa[3] = va.w;
        pb[0] = vb.x; pb[1] = vb.y; pb[2] = vb.z; pb[3] = vb.w;
    }
    if (tid < HC) sW[tid] = W2[h0 + tid];
    __syncthreads();

    float acc00 = 0.f, acc01 = 0.f, acc10 = 0.f, acc11 = 0.f;
    const float* pa0 = &sA[(2 * ty)     * LSTR];
    const float* pa1 = &sA[(2 * ty + 1) * LSTR];
    const float* pb0 = &sB[(2 * tx)     * LSTR];
    const float* pb1 = &sB[(2 * tx + 1) * LSTR];
    #pragma unroll 4
    for (int h = 0; h < HC; ++h) {
        const float w   = sW[h];               // contiguous -> compiler can b128
        const float a0  = pa0[h];
        const float a1  = pa1[h];
        const float b0v = pb0[h];
        const float b1v = pb1[h];
        acc00 = fmaf(fmaxf(a0 + b0v, 0.f), w, acc00);
        acc01 = fmaf(fmaxf(a0 + b1v, 0.f), w, acc01);
        acc10 = fmaf(fmaxf(a1 + b0v, 0.f), w, acc10);
        acc11 = fmaf(fmaxf(a1 + b1v, 0.f), w, acc11);
    }

    // ---- accumulate into out (zeroed before launch); z==0 adds the b2 bias
    const float bs = (blockIdx.z == 0) ? b2[0] : 0.0f;
    const int i = i0 + 2 * ty;
    const int j = j0 + 2 * tx;
    atomicAdd(&out[i * BATCH + j],           acc00 + bs);
    atomicAdd(&out[i * BATCH + j + 1],       acc01 + bs);
    atomicAdd(&out[(i + 1) * BATCH + j],     acc10 + bs);
    atomicAdd(&out[(i + 1) * BATCH + j + 1], acc11 + bs);
}

extern "C" void kernel_launch(void* const* d_in, const int* in_sizes, int n_in,
                              void* d_out, int out_size, void* d_ws, size_t ws_size,
                              hipStream_t stream) {
    const float* x  = (const float*)d_in[0];
    const float* y  = (const float*)d_in[1];
    const float* W1 = (const float*)d_in[2];
    const float* b1 = (const float*)d_in[3];
    const float* W2 = (const float*)d_in[4];
    const float* b2 = (const float*)d_in[5];
    float* out = (float*)d_out;
    float* hxy = (float*)d_ws;   // 1024 * 512 floats = 2 MiB scratch

    hipMemsetAsync(out, 0, BATCH * BATCH * sizeof(float), stream);
    proj_kernel<<<dim3(BATCH / 4, 2), 256, 0, stream>>>(x, y, W1, b1, hxy);
    score_kernel<<<dim3(BATCH / TB, BATCH / TB, HID / HC), 256, 0, stream>>>(hxy, W2, b2, out);
}

// Round 4
// 93.152 us; speedup vs baseline: 1.1764x; 1.0123x over previous
//
#include <hip/hip_runtime.h>

// ConcatCritic: scores[i,j] = W2 . relu(x_i@W1x + y_j@W1y + b1) + b2
// B=512, DIM_X=DIM_Y=128, HIDDEN=512. fp32 in/out.
//
// R4 (= R3 + compile fix): h-domain in f16. proj computes fp32, stores f16.
// score uses v_pk_add_f16 + v_pk_max_f16 + v_dot2_f32_f16 (fp32 acc)
// = 3 instr / 2 h per cell, halved LDS bytes, stride-33 conflict-free LDS,
// 4x2 register blocking, z=8 h-chunks, atomicAdd epilogue.

#define BATCH 512
#define DX    128
#define HID   512

typedef _Float16 half2_t __attribute__((ext_vector_type(2)));

static __device__ __forceinline__ half2_t u2h(unsigned int u) {
    union { unsigned int u; half2_t h; } c; c.u = u; return c.h;
}
static __device__ __forceinline__ unsigned int h2u(half2_t h) {
    union { half2_t h; unsigned int u; } c; c.h = h; return c.u;
}

// ---------------- Kernel A: projection (fp32 math, f16 out) ----------------
// hxy rows [0,512)    = x @ W1[:128]            (hx)
// hxy rows [512,1024) = y @ W1[128:256] + b1    (hy, bias folded)
__global__ __launch_bounds__(256) void proj_kernel(
    const float* __restrict__ x, const float* __restrict__ y,
    const float* __restrict__ W1, const float* __restrict__ b1,
    _Float16* __restrict__ hxy)
{
    const int part = blockIdx.y;                 // 0 -> x, 1 -> y
    const int row0 = blockIdx.x * 8;
    const int h    = blockIdx.z * 256 + threadIdx.x;
    const float* __restrict__ src = part ? y : x;
    const float* __restrict__ W   = W1 + part * DX * HID;

    __shared__ float s[8][DX];                   // 8 rows of input, 4 KiB
    {
        const int t = threadIdx.x;               // 256 float4 slots
        const int r = t >> 5, c4 = (t & 31) << 2;
        const float4 v = *(const float4*)&src[(row0 + r) * DX + c4];
        s[r][c4] = v.x; s[r][c4 + 1] = v.y; s[r][c4 + 2] = v.z; s[r][c4 + 3] = v.w;
    }
    __syncthreads();

    float acc[8] = {0.f, 0.f, 0.f, 0.f, 0.f, 0.f, 0.f, 0.f};
    #pragma unroll 4
    for (int k = 0; k < DX; ++k) {
        const float w = W[k * HID + h];          // coalesced across threads
        #pragma unroll
        for (int r = 0; r < 8; ++r) acc[r] = fmaf(s[r][k], w, acc[r]);
    }
    const float bias = part ? b1[h] : 0.0f;
    #pragma unroll
    for (int r = 0; r < 8; ++r)
        hxy[(part * BATCH + row0 + r) * HID + h] = (_Float16)(acc[r] + bias);
}

// ---------------- Kernel B: broadcast + relu + weighted reduce ----------------
// Tile: 64(i) x 32(j) per block, 256 threads, 4x2 cells/thread, HC=64 h per
// z-chunk (z=8). LDS rows stride 33 uints (odd) -> conflict-free scalar reads.
#define TI   64
#define TJ   32
#define HC   64
#define HPW  (HC / 2)    // 32 half2 per row
#define TS   33          // uint stride per LDS row

__global__ __launch_bounds__(256, 4) void score_kernel(
    const _Float16* __restrict__ hxy, const float* __restrict__ W2,
    const float* __restrict__ b2, float* __restrict__ out)
{
    __shared__ unsigned int sAu[TI * TS];        // hx tile, f16 pairs as uints
    __shared__ unsigned int sBu[TJ * TS];        // hy tile
    __shared__ unsigned int sWu[HPW];            // w2 as half2

    const int i0 = blockIdx.y * TI;
    const int j0 = blockIdx.x * TJ;
    const int h0 = blockIdx.z * HC;
    const int tid = threadIdx.x;

    // ---- stage: sA = 512 uint4 slots (8 per row), sB = 256, sW = 32
    {
        #pragma unroll
        for (int it = 0; it < 2; ++it) {         // sA
            const int s = tid + 256 * it;
            const int row = s >> 3, q = s & 7;   // q: 8-half groups
            const uint4 v = *(const uint4*)&hxy[(i0 + row) * HID + h0 + (q << 3)];
            unsigned int* p = &sAu[row * TS + (q << 2)];
            p[0] = v.x; p[1] = v.y; p[2] = v.z; p[3] = v.w;
        }
        {                                        // sB
            const int row = tid >> 3, q = tid & 7;
            const uint4 v = *(const uint4*)&hxy[(BATCH + j0 + row) * HID + h0 + (q << 3)];
            unsigned int* p = &sBu[row * TS + (q << 2)];
            p[0] = v.x; p[1] = v.y; p[2] = v.z; p[3] = v.w;
        }
        if (tid < HPW) {                         // sW: f32 -> half2 (rte)
            const float2 w = *(const float2*)&W2[h0 + 2 * tid];
            half2_t wh;
            wh.x = (_Float16)w.x;
            wh.y = (_Float16)w.y;
            sWu[tid] = h2u(wh);
        }
    }
    __syncthreads();

    const int tx = tid & 15;                     // j: 2 cols each -> 32
    const int ty = tid >> 4;                     // i: 4 rows each -> 64
    const unsigned int* pa = &sAu[(4 * ty) * TS];
    const unsigned int* pb = &sBu[(2 * tx) * TS];

    float acc[4][2] = {{0.f,0.f},{0.f,0.f},{0.f,0.f},{0.f,0.f}};
    const half2_t hz = {(_Float16)0, (_Float16)0};

    #pragma unroll 8
    for (int hp = 0; hp < HPW; ++hp) {
        const half2_t w  = u2h(sWu[hp]);
        const half2_t a0 = u2h(pa[hp]);
        const half2_t a1 = u2h(pa[TS + hp]);
        const half2_t a2 = u2h(pa[2 * TS + hp]);
        const half2_t a3 = u2h(pa[3 * TS + hp]);
        const half2_t b0 = u2h(pb[hp]);
        const half2_t b1v = u2h(pb[TS + hp]);
        half2_t a[4] = {a0, a1, a2, a3};
        half2_t b[2] = {b0, b1v};
        #pragma unroll
        for (int r = 0; r < 4; ++r)
            #pragma unroll
            for (int c = 0; c < 2; ++c) {
                half2_t t = a[r] + b[c];                       // v_pk_add_f16
                t = __builtin_elementwise_max(t, hz);          // v_pk_max_f16
                acc[r][c] = __builtin_amdgcn_fdot2(t, w, acc[r][c], false);
            }
    }

    const float bs = (blockIdx.z == 0) ? b2[0] : 0.0f;
    const int i = i0 + 4 * ty;
    const int j = j0 + 2 * tx;
    #pragma unroll
    for (int r = 0; r < 4; ++r) {
        atomicAdd(&out[(i + r) * BATCH + j],     acc[r][0] + bs);
        atomicAdd(&out[(i + r) * BATCH + j + 1], acc[r][1] + bs);
    }
}

extern "C" void kernel_launch(void* const* d_in, const int* in_sizes, int n_in,
                              void* d_out, int out_size, void* d_ws, size_t ws_size,
                              hipStream_t stream) {
    const float* x  = (const float*)d_in[0];
    const float* y  = (const float*)d_in[1];
    const float* W1 = (const float*)d_in[2];
    const float* b1 = (const float*)d_in[3];
    const float* W2 = (const float*)d_in[4];
    const float* b2 = (const float*)d_in[5];
    float* out = (float*)d_out;
    _Float16* hxy = (_Float16*)d_ws;             // 1024*512 halves = 1 MiB

    (void)hipMemsetAsync(out, 0, BATCH * BATCH * sizeof(float), stream);
    proj_kernel<<<dim3(BATCH / 8, 2, 2), 256, 0, stream>>>(x, y, W1, b1, hxy);
    score_kernel<<<dim3(BATCH / TJ, BATCH / TI, HID / HC), 256, 0, stream>>>(hxy, W2, b2, out);
}

// Round 5
// 88.714 us; speedup vs baseline: 1.2352x; 1.0500x over previous
//
#include <hip/hip_runtime.h>

// ConcatCritic: scores[i,j] = W2 . relu(x_i@W1x + y_j@W1y + b1) + b2
// B=512, DIM_X=DIM_Y=128, HIDDEN=512. fp32 in/out.
//
// R5: no atomics / no memset. proj (fp32 math -> f16 ws). score: TI=128 x
// TJ=64 tile, 512 threads, 4x4 cells/thread (LDS bytes 0.56 uint/cell-hpair,
// VALU-bound), z=8 h-chunks writing fp32 partials to ws. reduce: sum 8
// partial slices + b2 -> out.

#define BATCH 512
#define DX    128
#define HID   512

typedef _Float16 half2_t __attribute__((ext_vector_type(2)));

static __device__ __forceinline__ half2_t u2h(unsigned int u) {
    union { unsigned int u; half2_t h; } c; c.u = u; return c.h;
}
static __device__ __forceinline__ unsigned int h2u(half2_t h) {
    union { half2_t h; unsigned int u; } c; c.h = h; return c.u;
}

// ---------------- Kernel A: projection (fp32 math, f16 out) ----------------
__global__ __launch_bounds__(256) void proj_kernel(
    const float* __restrict__ x, const float* __restrict__ y,
    const float* __restrict__ W1, const float* __restrict__ b1,
    _Float16* __restrict__ hxy)
{
    const int part = blockIdx.y;                 // 0 -> x, 1 -> y
    const int row0 = blockIdx.x * 8;
    const int h    = blockIdx.z * 256 + threadIdx.x;
    const float* __restrict__ src = part ? y : x;
    const float* __restrict__ W   = W1 + part * DX * HID;

    __shared__ float s[8][DX];
    {
        const int t = threadIdx.x;               // 256 float4 slots
        const int r = t >> 5, c4 = (t & 31) << 2;
        const float4 v = *(const float4*)&src[(row0 + r) * DX + c4];
        s[r][c4] = v.x; s[r][c4 + 1] = v.y; s[r][c4 + 2] = v.z; s[r][c4 + 3] = v.w;
    }
    __syncthreads();

    float acc[8] = {0.f, 0.f, 0.f, 0.f, 0.f, 0.f, 0.f, 0.f};
    #pragma unroll 4
    for (int k = 0; k < DX; ++k) {
        const float w = W[k * HID + h];
        #pragma unroll
        for (int r = 0; r < 8; ++r) acc[r] = fmaf(s[r][k], w, acc[r]);
    }
    const float bias = part ? b1[h] : 0.0f;
    #pragma unroll
    for (int r = 0; r < 8; ++r)
        hxy[(part * BATCH + row0 + r) * HID + h] = (_Float16)(acc[r] + bias);
}

// ---------------- Kernel B: score partials ----------------
// Tile 128(i) x 64(j), 512 threads, 4x4 cells/thread, HC=64 h per z (z=8).
// Grid 8x4x8 = 256 blocks, 8 waves/block = 2 waves/SIMD.
// LDS stride 33 uints: a-reads broadcast (4 addrs/wave), b-reads 2-way (free).
#define TI   128
#define TJ   64
#define HC   64
#define HPW  (HC / 2)    // 32 half2 per chunk
#define ST   33          // uint stride per LDS row

__global__ __launch_bounds__(512, 2) void score_kernel(
    const _Float16* __restrict__ hxy, const float* __restrict__ W2,
    float* __restrict__ pws)
{
    __shared__ unsigned int sA[TI * ST];         // 16.9 KiB
    __shared__ unsigned int sB[TJ * ST];         //  8.5 KiB
    __shared__ unsigned int sW[HPW];

    const int i0 = blockIdx.y * TI;
    const int j0 = blockIdx.x * TJ;
    const int hp0 = blockIdx.z * HPW;            // in half2 units
    const int tid = threadIdx.x;
    const unsigned int* __restrict__ hx32 = (const unsigned int*)hxy; // [row][256 hp]

    // ---- stage A: 1024 uint4 slots (2/thread), B: 512 (1/thread), W: 32
    #pragma unroll
    for (int it = 0; it < 2; ++it) {
        const int s = tid + it * 512;
        const int row = s >> 3, q = s & 7;       // 8 uint4 per row
        const uint4 v = *(const uint4*)&hx32[(i0 + row) * 256 + hp0 + (q << 2)];
        unsigned int* p = &sA[row * ST + (q << 2)];
        p[0] = v.x; p[1] = v.y; p[2] = v.z; p[3] = v.w;
    }
    {
        const int row = tid >> 3, q = tid & 7;
        const uint4 v = *(const uint4*)&hx32[(BATCH + j0 + row) * 256 + hp0 + (q << 2)];
        unsigned int* p = &sB[row * ST + (q << 2)];
        p[0] = v.x; p[1] = v.y; p[2] = v.z; p[3] = v.w;
    }
    if (tid < HPW) {
        const float2 w = *(const float2*)&W2[2 * (hp0 + tid)];
        half2_t wh; wh.x = (_Float16)w.x; wh.y = (_Float16)w.y;
        sW[tid] = h2u(wh);
    }
    __syncthreads();

    const int tx = tid & 15;                     // 4 cols each -> 64
    const int ty = tid >> 4;                     // 0..31, 4 rows each -> 128
    const unsigned int* pa = &sA[(ty << 2) * ST];
    const unsigned int* pb = &sB[(tx << 2) * ST];

    float acc[4][4] = {{0.f,0.f,0.f,0.f},{0.f,0.f,0.f,0.f},
                       {0.f,0.f,0.f,0.f},{0.f,0.f,0.f,0.f}};
    const half2_t hz = {(_Float16)0, (_Float16)0};

    #pragma unroll 4
    for (int hp = 0; hp < HPW; ++hp) {
        const half2_t w = u2h(sW[hp]);
        half2_t a[4], b[4];
        #pragma unroll
        for (int r = 0; r < 4; ++r) a[r] = u2h(pa[r * ST + hp]);
        #pragma unroll
        for (int c = 0; c < 4; ++c) b[c] = u2h(pb[c * ST + hp]);
        #pragma unroll
        for (int r = 0; r < 4; ++r)
            #pragma unroll
            for (int c = 0; c < 4; ++c) {
                half2_t t = a[r] + b[c];                   // v_pk_add_f16
                t = __builtin_elementwise_max(t, hz);      // v_pk_max_f16
                acc[r][c] = __builtin_amdgcn_fdot2(t, w, acc[r][c], false);
            }
    }

    // ---- coalesced float4 partial stores (256 B contiguous per ty-row)
    float* dst = pws + blockIdx.z * (BATCH * BATCH);
    const int i = i0 + (ty << 2);
    const int j = j0 + (tx << 2);
    #pragma unroll
    for (int r = 0; r < 4; ++r) {
        float4 v = make_float4(acc[r][0], acc[r][1], acc[r][2], acc[r][3]);
        *(float4*)&dst[(i + r) * BATCH + j] = v;
    }
}

// ---------------- Kernel C: reduce 8 partial slices + b2 ----------------
__global__ __launch_bounds__(256) void reduce_kernel(
    const float* __restrict__ pws, const float* __restrict__ b2,
    float* __restrict__ out)
{
    const int idx4 = blockIdx.x * 256 + threadIdx.x;     // 0..65535 float4s
    const float4* __restrict__ p4 = (const float4*)pws;
    float4 s = p4[idx4];
    #pragma unroll
    for (int z = 1; z < 8; ++z) {
        const float4 v = p4[z * (BATCH * BATCH / 4) + idx4];
        s.x += v.x; s.y += v.y; s.z += v.z; s.w += v.w;
    }
    const float bs = b2[0];
    s.x += bs; s.y += bs; s.z += bs; s.w += bs;
    ((float4*)out)[idx4] = s;
}

extern "C" void kernel_launch(void* const* d_in, const int* in_sizes, int n_in,
                              void* d_out, int out_size, void* d_ws, size_t ws_size,
                              hipStream_t stream) {
    const float* x  = (const float*)d_in[0];
    const float* y  = (const float*)d_in[1];
    const float* W1 = (const float*)d_in[2];
    const float* b1 = (const float*)d_in[3];
    const float* W2 = (const float*)d_in[4];
    const float* b2 = (const float*)d_in[5];
    float* out = (float*)d_out;

    _Float16* hxy = (_Float16*)d_ws;                       // 1 MiB
    float* pws = (float*)((char*)d_ws + (1 << 20));        // 8 MiB partials

    proj_kernel<<<dim3(BATCH / 8, 2, 2), 256, 0, stream>>>(x, y, W1, b1, hxy);
    score_kernel<<<dim3(BATCH / TJ, BATCH / TI, HID / HC), 512, 0, stream>>>(hxy, W2, pws);
    reduce_kernel<<<dim3(BATCH * BATCH / 4 / 256), 256, 0, stream>>>(pws, b2, out);
}